// Round 4
// baseline (201.825 us; speedup 1.0000x reference)
//
#include <hip/hip_runtime.h>

// EntityLinker forward, MI355X/gfx950. One block per batch b, 256 thr (4 waves).
// R4: LDS 40960B -> 4 blocks/CU (no grid tail). QHT dropped (P4-B via swizzled
// scalar ds reads of q_h), att in scratch, qsum via global ws, P5 row-split
// with direct out writes, native __bf16 casts.

typedef __attribute__((ext_vector_type(8))) short     short8;
typedef __attribute__((ext_vector_type(8))) __bf16    bf16x8;
typedef __attribute__((ext_vector_type(4))) float     f32x4;
typedef __attribute__((ext_vector_type(4))) int       int4v;

#define SWZ8(row, off) ((off) ^ (((row) & 7) << 4))
#define SWZQ(row, off) ((off) ^ (((row) & 7) << 4) ^ ((((row) >> 3) & 3) << 5))

// ---- LDS layout (bytes), total 40960 = 4 blocks/CU exactly ----
#define CH_OFF  0        // c_h [64][128] bf16, 256B rows, SWZ8
#define QH_OFF  16384    // q_h [64][128] bf16, 256B rows, SWZQ  -> wq in P5
#define SC_OFF  32768    // P1-P2: qsum partials [16][128] f32 ; P3e-P4: att [64][64] bf16 SWZ8
#define LDS_SIZE 40960

__device__ __forceinline__ unsigned short f2bf(float x) {
    __bf16 h = (__bf16)x;                       // native RNE cvt (cvt_pk-fusable)
    return __builtin_bit_cast(unsigned short, h);
}
__device__ __forceinline__ float bf2f(unsigned short u) {
    return __builtin_bit_cast(float, ((unsigned)u) << 16);
}
__device__ __forceinline__ float bflo(unsigned u) {
    return __builtin_bit_cast(float, u << 16);
}
__device__ __forceinline__ float bfhi(unsigned u) {
    return __builtin_bit_cast(float, u & 0xFFFF0000u);
}
__device__ __forceinline__ unsigned pk2(float a, float b) {
    return (unsigned)f2bf(a) | ((unsigned)f2bf(b) << 16);
}
__device__ __forceinline__ f32x4 mfma16(short8 a, short8 b, f32x4 c) {
    return __builtin_amdgcn_mfma_f32_16x16x32_bf16(
        __builtin_bit_cast(bf16x8, a), __builtin_bit_cast(bf16x8, b), c, 0, 0, 0);
}

// W_h [640][128] f32 -> whT [128][640] bf16.
__global__ __launch_bounds__(256) void el_prep(const float* __restrict__ W_h,
                                               unsigned short* __restrict__ whT) {
    int t = blockIdx.x * 256 + threadIdx.x;
    int k = t >> 7, n = t & 127;
    whT[n * 640 + k] = f2bf(W_h[t]);
}

// embed f32 [100000][128] -> bf16 table in ws.
__global__ __launch_bounds__(256) void el_conv(const float* __restrict__ e,
                                               unsigned short* __restrict__ ebf) {
    long i = ((long)blockIdx.x * 256 + threadIdx.x) * 8;
    f32x4 a = *(const f32x4*)(e + i);
    f32x4 c = *(const f32x4*)(e + i + 4);
    uint4 pk;
    pk.x = pk2(a[0], a[1]); pk.y = pk2(a[2], a[3]);
    pk.z = pk2(c[0], c[1]); pk.w = pk2(c[2], c[3]);
    *(uint4*)(ebf + i) = pk;
}

template <bool BF16E>
__global__ __launch_bounds__(256, 4) void el_main(
    const int* __restrict__ q_ids, const int* __restrict__ c_ids,
    const int* __restrict__ num_qs, const float* __restrict__ emb,
    const unsigned short* __restrict__ ebf,
    const unsigned short* __restrict__ whT,
    unsigned short* __restrict__ qsum_ws,
    const float* __restrict__ b_h,
    const float* __restrict__ W_o, const float* __restrict__ b_o,
    float* __restrict__ out)
{
    __shared__ __align__(16) char smem[LDS_SIZE];
    const int tid = threadIdx.x;
    const int b = blockIdx.x;
    const int nq = num_qs[b] > 0 ? num_qs[b] : 1;

    // ---------------- P1: gathers ----------------
    {
        const int l4 = tid & 15, gg = tid >> 4;       // 16 groups of 16 lanes
        // c_h: masked mean over 8 tokens; group gg handles cols gg, gg+16, ...
        #pragma unroll 2
        for (int cc = 0; cc < 4; ++cc) {
            const int c = gg + cc * 16;
            const int* idp = c_ids + (((b << 6) + c) << 3);
            int4v i0 = *(const int4v*)idp, i1 = *(const int4v*)(idp + 4);
            int id8[8] = {i0[0], i0[1], i0[2], i0[3], i1[0], i1[1], i1[2], i1[3]};
            int cnt = 0;
            #pragma unroll
            for (int t = 0; t < 8; ++t) cnt += (id8[t] != 0);
            float acc[8] = {0.f,0.f,0.f,0.f,0.f,0.f,0.f,0.f};
            #pragma unroll
            for (int t = 0; t < 8; ++t) {
                if constexpr (BF16E) {
                    uint4 v = *(const uint4*)(ebf + (long)id8[t] * 128 + l4 * 8);
                    acc[0] += bflo(v.x); acc[1] += bfhi(v.x);
                    acc[2] += bflo(v.y); acc[3] += bfhi(v.y);
                    acc[4] += bflo(v.z); acc[5] += bfhi(v.z);
                    acc[6] += bflo(v.w); acc[7] += bfhi(v.w);
                } else {
                    f32x4 lo = *(const f32x4*)(emb + (long)id8[t] * 128 + l4 * 8);
                    f32x4 hi = *(const f32x4*)(emb + (long)id8[t] * 128 + l4 * 8 + 4);
                    acc[0] += lo[0]; acc[1] += lo[1]; acc[2] += lo[2]; acc[3] += lo[3];
                    acc[4] += hi[0]; acc[5] += hi[1]; acc[6] += hi[2]; acc[7] += hi[3];
                }
            }
            float inv = 1.0f / (float)(cnt > 0 ? cnt : 1);
            uint4 pk;
            pk.x = pk2(acc[0]*inv, acc[1]*inv); pk.y = pk2(acc[2]*inv, acc[3]*inv);
            pk.z = pk2(acc[4]*inv, acc[5]*inv); pk.w = pk2(acc[6]*inv, acc[7]*inv);
            *(uint4*)(smem + CH_OFF + SWZ8(c, c * 256 + l4 * 16)) = pk;
        }
        // q_h copy + masked q_summary partials
        float qa[8] = {0.f,0.f,0.f,0.f,0.f,0.f,0.f,0.f};
        #pragma unroll
        for (int qq = 0; qq < 4; ++qq) {
            const int q = gg + (qq << 4);
            int id = q_ids[(b << 6) + q];
            uint4 v;
            if constexpr (BF16E) {
                v = *(const uint4*)(ebf + (long)id * 128 + l4 * 8);
            } else {
                f32x4 lo = *(const f32x4*)(emb + (long)id * 128 + l4 * 8);
                f32x4 hi = *(const f32x4*)(emb + (long)id * 128 + l4 * 8 + 4);
                v.x = pk2(lo[0], lo[1]); v.y = pk2(lo[2], lo[3]);
                v.z = pk2(hi[0], hi[1]); v.w = pk2(hi[2], hi[3]);
            }
            *(uint4*)(smem + QH_OFF + SWZQ(q, q * 256 + l4 * 16)) = v;
            if (q < nq) {
                qa[0] += bflo(v.x); qa[1] += bfhi(v.x);
                qa[2] += bflo(v.y); qa[3] += bfhi(v.y);
                qa[4] += bflo(v.z); qa[5] += bfhi(v.z);
                qa[6] += bflo(v.w); qa[7] += bfhi(v.w);
            }
        }
        float* qsp = (float*)(smem + SC_OFF);
        *(f32x4*)(qsp + gg * 128 + l4 * 8)     = (f32x4){qa[0], qa[1], qa[2], qa[3]};
        *(f32x4*)(qsp + gg * 128 + l4 * 8 + 4) = (f32x4){qa[4], qa[5], qa[6], qa[7]};
    }
    __syncthreads();

    // ---------------- P2: q_summary -> global ws (bf16) ----------------
    if (tid < 128) {
        const float* qsp = (const float*)(smem + SC_OFF);
        float s = 0.f;
        #pragma unroll
        for (int g = 0; g < 16; ++g) s += qsp[g * 128 + tid];
        qsum_ws[(b << 7) + tid] = f2bf(s / (float)nq);
    }
    __syncthreads();

    const int lane = tid & 63, w = tid >> 6;
    const int lr = lane & 15, lg = lane >> 4;

    // ---------------- P3: sim + in-reg softmax -> att in SC ----------------
    {
        short8 a[4];
        const int arow = w * 16 + lr;
        #pragma unroll
        for (int s = 0; s < 4; ++s)
            a[s] = *(const short8*)(smem + CH_OFF + SWZ8(arow, arow * 256 + s * 64 + lg * 16));
        f32x4 sim[4];
        #pragma unroll
        for (int ct = 0; ct < 4; ++ct) {
            f32x4 acc = {0.f, 0.f, 0.f, 0.f};
            const int q = ct * 16 + lr;
            #pragma unroll
            for (int s = 0; s < 4; ++s) {
                short8 bf = *(const short8*)(smem + QH_OFF + SWZQ(q, q * 256 + s * 64 + lg * 16));
                acc = mfma16(a[s], bf, acc);
            }
            sim[ct] = acc;
        }
        const float scale = 0.08838834764831845f;  // 1/sqrt(128)
        #pragma unroll
        for (int ct = 0; ct < 4; ++ct) {
            const int q = ct * 16 + lr;
            #pragma unroll
            for (int r = 0; r < 4; ++r)
                sim[ct][r] = (q < nq) ? sim[ct][r] * scale : -3.0e38f;
        }
        float mx[4], sm[4];
        #pragma unroll
        for (int r = 0; r < 4; ++r)
            mx[r] = fmaxf(fmaxf(sim[0][r], sim[1][r]), fmaxf(sim[2][r], sim[3][r]));
        #pragma unroll
        for (int off = 1; off <= 8; off <<= 1)
            #pragma unroll
            for (int r = 0; r < 4; ++r)
                mx[r] = fmaxf(mx[r], __shfl_xor(mx[r], off));
        #pragma unroll
        for (int ct = 0; ct < 4; ++ct)
            #pragma unroll
            for (int r = 0; r < 4; ++r)
                sim[ct][r] = __expf(sim[ct][r] - mx[r]);
        #pragma unroll
        for (int r = 0; r < 4; ++r)
            sm[r] = (sim[0][r] + sim[1][r]) + (sim[2][r] + sim[3][r]);
        #pragma unroll
        for (int off = 1; off <= 8; off <<= 1)
            #pragma unroll
            for (int r = 0; r < 4; ++r)
                sm[r] += __shfl_xor(sm[r], off);
        // att -> SC region (qsum partials consumed in P2; barrier above separates)
        const int cbase = w * 16 + lg * 4;
        #pragma unroll
        for (int ct = 0; ct < 4; ++ct)
            #pragma unroll
            for (int r = 0; r < 4; ++r) {
                int c = cbase + r, q = ct * 16 + lr;
                *(unsigned short*)(smem + SC_OFF + SWZ8(c, c * 128 + q * 2)) =
                    f2bf(sim[ct][r] * (1.0f / sm[r]));
            }
    }
    __syncthreads();

    // ---------------- P4: weighted_q = att @ q_h ----------------
    f32x4 wqa[8];
    {
        short8 pa[2];
        const int arow = w * 16 + lr;
        #pragma unroll
        for (int s = 0; s < 2; ++s)
            pa[s] = *(const short8*)(smem + SC_OFF + SWZ8(arow, arow * 128 + s * 64 + lg * 16));
        const int d2 = (lr << 1);  // d*2 byte offset base built per ct below
        #pragma unroll
        for (int ct = 0; ct < 8; ++ct) {
            f32x4 acc = {0.f, 0.f, 0.f, 0.f};
            const int d = ct * 16 + lr;
            const int dlx = (d << 1) ^ (lg << 5);
            #pragma unroll
            for (int s = 0; s < 2; ++s) {
                const int qbase = (s << 5) + (lg << 3);
                short8 bf;
                #pragma unroll
                for (int j = 0; j < 8; ++j) {
                    // SWZQ(q, q*256 + d*2), q = qbase+j; (q&7)=j, ((q>>3)&3)=lg
                    int off = QH_OFF + ((qbase + j) << 8) + (dlx ^ (j << 4));
                    bf[j] = *(const short*)(smem + off);
                }
                acc = mfma16(pa[s], bf, acc);
            }
            wqa[ct] = acc;
        }
        (void)d2;
    }
    __syncthreads();   // q_h reads done -> wq overwrites QH
    {
        const int cbase = w * 16 + lg * 4;
        #pragma unroll
        for (int ct = 0; ct < 8; ++ct)
            #pragma unroll
            for (int r = 0; r < 4; ++r) {
                int c = cbase + r, d = ct * 16 + lr;
                *(unsigned short*)(smem + QH_OFF + SWZQ(c, c * 256 + d * 2)) =
                    f2bf(wqa[ct][r]);
            }
    }
    __syncthreads();

    // ---------------- P5: row-split GEMM + tanh + W_o, direct out ----------
    {
        f32x4 acc[8];
        #pragma unroll
        for (int nt = 0; nt < 8; ++nt) acc[nt] = (f32x4){0.f, 0.f, 0.f, 0.f};

        short8 qsf[4];
        #pragma unroll
        for (int sk = 0; sk < 4; ++sk)
            qsf[sk] = *(const short8*)(qsum_ws + (b << 7) + sk * 32 + lg * 8);
        float bh[8], wo[8];
        #pragma unroll
        for (int nt = 0; nt < 8; ++nt) {
            bh[nt] = b_h[nt * 16 + lr];
            wo[nt] = W_o[nt * 16 + lr];
        }
        const int row = w * 16 + lr;

        #pragma unroll
        for (int sk = 0; sk < 4; ++sk) {
            short8 chf = *(const short8*)(smem + CH_OFF + SWZ8(row, row * 256 + sk * 64 + lg * 16));
            short8 wqf = *(const short8*)(smem + QH_OFF + SWZQ(row, row * 256 + sk * 64 + lg * 16));
            short8 prf, adf;
            #pragma unroll
            for (int e = 0; e < 8; ++e) {
                float cv = bf2f((unsigned short)chf[e]);
                float wv = bf2f((unsigned short)wqf[e]);
                prf[e] = (short)f2bf(cv * wv);
                adf[e] = (short)f2bf(fabsf(cv - wv));
            }
            const unsigned short* wp = whT + sk * 32 + lg * 8;
            #pragma unroll
            for (int nt = 0; nt < 8; ++nt) {
                const unsigned short* wpn = wp + (nt * 16 + lr) * 640;
                acc[nt] = mfma16(qsf[sk], *(const short8*)(wpn      ), acc[nt]);
                acc[nt] = mfma16(chf,     *(const short8*)(wpn + 128), acc[nt]);
                acc[nt] = mfma16(wqf,     *(const short8*)(wpn + 256), acc[nt]);
                acc[nt] = mfma16(prf,     *(const short8*)(wpn + 384), acc[nt]);
                acc[nt] = mfma16(adf,     *(const short8*)(wpn + 512), acc[nt]);
            }
        }

        float po[4] = {0.f, 0.f, 0.f, 0.f};
        #pragma unroll
        for (int nt = 0; nt < 8; ++nt)
            #pragma unroll
            for (int r = 0; r < 4; ++r) {
                float x = acc[nt][r] + bh[nt];
                float t = 1.0f - 2.0f / (__expf(2.0f * x) + 1.0f);  // tanh
                po[r] += t * wo[nt];
            }
        #pragma unroll
        for (int off = 1; off <= 8; off <<= 1)
            #pragma unroll
            for (int r = 0; r < 4; ++r)
                po[r] += __shfl_xor(po[r], off);
        if (lr == 0) {
            float bo = b_o[0];
            f32x4 o = {po[0] + bo, po[1] + bo, po[2] + bo, po[3] + bo};
            *(f32x4*)(out + (b << 6) + w * 16 + lg * 4) = o;
        }
    }
}

extern "C" void kernel_launch(void* const* d_in, const int* in_sizes, int n_in,
                              void* d_out, int out_size, void* d_ws, size_t ws_size,
                              hipStream_t stream) {
    const int*   q_ids  = (const int*)d_in[0];
    const int*   c_ids  = (const int*)d_in[1];
    const int*   num_qs = (const int*)d_in[2];
    // d_in[3] num_cols: unused by the reference forward
    const float* embed  = (const float*)d_in[4];
    const float* W_h    = (const float*)d_in[5];
    const float* b_h    = (const float*)d_in[6];
    const float* W_o    = (const float*)d_in[7];
    const float* b_o    = (const float*)d_in[8];
    float*       out    = (float*)d_out;

    // ws: [0,160K) whT | [160K, 416K) qsum bf16 [1024][128] | [416K, +25.6M) ebf
    unsigned short* whT  = (unsigned short*)d_ws;
    unsigned short* qsum = (unsigned short*)((char*)d_ws + 163840);
    unsigned short* ebf  = (unsigned short*)((char*)d_ws + 425984);

    el_prep<<<320, 256, 0, stream>>>(W_h, whT);

    const bool bf16e = ws_size >= (size_t)(425984 + 100000 * 128 * 2);
    if (bf16e) {
        el_conv<<<6250, 256, 0, stream>>>(embed, ebf);
        el_main<true><<<1024, 256, 0, stream>>>(q_ids, c_ids, num_qs, embed, ebf,
                                                whT, qsum, b_h, W_o, b_o, out);
    } else {
        el_main<false><<<1024, 256, 0, stream>>>(q_ids, c_ids, num_qs, embed, ebf,
                                                 whT, qsum, b_h, W_o, b_o, out);
    }
}

// Round 5
// 151.202 us; speedup vs baseline: 1.3348x; 1.3348x over previous
//
#include <hip/hip_runtime.h>

// EntityLinker forward, MI355X/gfx950. One block per batch b, 256 thr (4 waves).
// R5: R3's fast column-split P5 restored + 4 blocks/CU (LDS exactly 40960B).
// X region (8KB) time-shared: qsum partials (P1-P2) -> att (P3-P4) -> out
// partials (P5-P6). P4 B-operand via conflict-free scalar SWZQ ds reads.

typedef __attribute__((ext_vector_type(8))) short     short8;
typedef __attribute__((ext_vector_type(8))) __bf16    bf16x8;
typedef __attribute__((ext_vector_type(4))) float     f32x4;
typedef __attribute__((ext_vector_type(4))) int       int4v;

#define SWZ8(row, off) ((off) ^ (((row) & 7) << 4))
#define SWZQ(row, off) ((off) ^ (((row) & 7) << 4) ^ ((((row) >> 3) & 3) << 5))

// ---- LDS layout (bytes), total 40960 = 4 blocks/CU exactly ----
#define CH_OFF  0        // c_h [64][128] bf16, 256B rows, SWZ8
#define QH_OFF  16384    // q_h [64][128] bf16, 256B rows, SWZQ -> wq after P4
#define X_OFF   32768    // P1-P2: qsum partials [16][128] f32 (8KB)
                         // P3-P4: att [64][64] bf16, 128B rows, SWZ8 (8KB)
                         // P5-P6: out partials [4][64] f32 (1KB)
#define LDS_SIZE 40960

__device__ __forceinline__ unsigned short f2bf(float x) {
    __bf16 h = (__bf16)x;
    return __builtin_bit_cast(unsigned short, h);
}
__device__ __forceinline__ float bf2f(unsigned short u) {
    return __builtin_bit_cast(float, ((unsigned)u) << 16);
}
__device__ __forceinline__ float bflo(unsigned u) {
    return __builtin_bit_cast(float, u << 16);
}
__device__ __forceinline__ float bfhi(unsigned u) {
    return __builtin_bit_cast(float, u & 0xFFFF0000u);
}
__device__ __forceinline__ unsigned pk2(float a, float b) {
    return (unsigned)f2bf(a) | ((unsigned)f2bf(b) << 16);
}
__device__ __forceinline__ f32x4 mfma16(short8 a, short8 b, f32x4 c) {
    return __builtin_amdgcn_mfma_f32_16x16x32_bf16(
        __builtin_bit_cast(bf16x8, a), __builtin_bit_cast(bf16x8, b), c, 0, 0, 0);
}

// W_h [640][128] f32 -> whT [128][640] bf16.
__global__ __launch_bounds__(256) void el_prep(const float* __restrict__ W_h,
                                               unsigned short* __restrict__ whT) {
    int t = blockIdx.x * 256 + threadIdx.x;
    int k = t >> 7, n = t & 127;
    whT[n * 640 + k] = f2bf(W_h[t]);
}

// embed f32 [100000][128] -> bf16 table in ws.
__global__ __launch_bounds__(256) void el_conv(const float* __restrict__ e,
                                               unsigned short* __restrict__ ebf) {
    long i = ((long)blockIdx.x * 256 + threadIdx.x) * 8;
    f32x4 a = *(const f32x4*)(e + i);
    f32x4 c = *(const f32x4*)(e + i + 4);
    uint4 pk;
    pk.x = pk2(a[0], a[1]); pk.y = pk2(a[2], a[3]);
    pk.z = pk2(c[0], c[1]); pk.w = pk2(c[2], c[3]);
    *(uint4*)(ebf + i) = pk;
}

template <bool BF16E>
__global__ __launch_bounds__(256, 4) void el_main(
    const int* __restrict__ q_ids, const int* __restrict__ c_ids,
    const int* __restrict__ num_qs, const float* __restrict__ emb,
    const unsigned short* __restrict__ ebf,
    const unsigned short* __restrict__ whT,
    unsigned short* __restrict__ qsum_ws,
    const float* __restrict__ b_h,
    const float* __restrict__ W_o, const float* __restrict__ b_o,
    float* __restrict__ out)
{
    __shared__ __align__(16) char smem[LDS_SIZE];
    const int tid = threadIdx.x;
    const int b = blockIdx.x;
    const int nq = num_qs[b] > 0 ? num_qs[b] : 1;

    // ---------------- P1: gathers ----------------
    {
        const int l4 = tid & 15, gg = tid >> 4;       // 16 groups of 16 lanes
        #pragma unroll 2
        for (int cc = 0; cc < 4; ++cc) {
            const int c = gg + cc * 16;
            const int* idp = c_ids + (((b << 6) + c) << 3);
            int4v i0 = *(const int4v*)idp, i1 = *(const int4v*)(idp + 4);
            int id8[8] = {i0[0], i0[1], i0[2], i0[3], i1[0], i1[1], i1[2], i1[3]};
            int cnt = 0;
            #pragma unroll
            for (int t = 0; t < 8; ++t) cnt += (id8[t] != 0);
            float acc[8] = {0.f,0.f,0.f,0.f,0.f,0.f,0.f,0.f};
            #pragma unroll
            for (int t = 0; t < 8; ++t) {
                if constexpr (BF16E) {
                    uint4 v = *(const uint4*)(ebf + (long)id8[t] * 128 + l4 * 8);
                    acc[0] += bflo(v.x); acc[1] += bfhi(v.x);
                    acc[2] += bflo(v.y); acc[3] += bfhi(v.y);
                    acc[4] += bflo(v.z); acc[5] += bfhi(v.z);
                    acc[6] += bflo(v.w); acc[7] += bfhi(v.w);
                } else {
                    f32x4 lo = *(const f32x4*)(emb + (long)id8[t] * 128 + l4 * 8);
                    f32x4 hi = *(const f32x4*)(emb + (long)id8[t] * 128 + l4 * 8 + 4);
                    acc[0] += lo[0]; acc[1] += lo[1]; acc[2] += lo[2]; acc[3] += lo[3];
                    acc[4] += hi[0]; acc[5] += hi[1]; acc[6] += hi[2]; acc[7] += hi[3];
                }
            }
            float inv = 1.0f / (float)(cnt > 0 ? cnt : 1);
            uint4 pk;
            pk.x = pk2(acc[0]*inv, acc[1]*inv); pk.y = pk2(acc[2]*inv, acc[3]*inv);
            pk.z = pk2(acc[4]*inv, acc[5]*inv); pk.w = pk2(acc[6]*inv, acc[7]*inv);
            *(uint4*)(smem + CH_OFF + SWZ8(c, c * 256 + l4 * 16)) = pk;
        }
        // q_h copy + masked q_summary partials
        float qa[8] = {0.f,0.f,0.f,0.f,0.f,0.f,0.f,0.f};
        #pragma unroll
        for (int qq = 0; qq < 4; ++qq) {
            const int q = gg + (qq << 4);
            int id = q_ids[(b << 6) + q];
            uint4 v;
            if constexpr (BF16E) {
                v = *(const uint4*)(ebf + (long)id * 128 + l4 * 8);
            } else {
                f32x4 lo = *(const f32x4*)(emb + (long)id * 128 + l4 * 8);
                f32x4 hi = *(const f32x4*)(emb + (long)id * 128 + l4 * 8 + 4);
                v.x = pk2(lo[0], lo[1]); v.y = pk2(lo[2], lo[3]);
                v.z = pk2(hi[0], hi[1]); v.w = pk2(hi[2], hi[3]);
            }
            *(uint4*)(smem + QH_OFF + SWZQ(q, q * 256 + l4 * 16)) = v;
            if (q < nq) {
                qa[0] += bflo(v.x); qa[1] += bfhi(v.x);
                qa[2] += bflo(v.y); qa[3] += bfhi(v.y);
                qa[4] += bflo(v.z); qa[5] += bfhi(v.z);
                qa[6] += bflo(v.w); qa[7] += bfhi(v.w);
            }
        }
        float* qsp = (float*)(smem + X_OFF);
        *(f32x4*)(qsp + gg * 128 + l4 * 8)     = (f32x4){qa[0], qa[1], qa[2], qa[3]};
        *(f32x4*)(qsp + gg * 128 + l4 * 8 + 4) = (f32x4){qa[4], qa[5], qa[6], qa[7]};
    }
    __syncthreads();

    // ---------------- P2: q_summary -> global ws (bf16) ----------------
    if (tid < 128) {
        const float* qsp = (const float*)(smem + X_OFF);
        float s = 0.f;
        #pragma unroll
        for (int g = 0; g < 16; ++g) s += qsp[g * 128 + tid];
        qsum_ws[(b << 7) + tid] = f2bf(s / (float)nq);
    }
    __syncthreads();

    const int lane = tid & 63, w = tid >> 6;
    const int lr = lane & 15, lg = lane >> 4;

    // ---------------- P3: sim + in-reg softmax -> att in X ----------------
    {
        short8 a[4];
        const int arow = w * 16 + lr;
        #pragma unroll
        for (int s = 0; s < 4; ++s)
            a[s] = *(const short8*)(smem + CH_OFF + SWZ8(arow, arow * 256 + s * 64 + lg * 16));
        f32x4 sim[4];
        #pragma unroll
        for (int ct = 0; ct < 4; ++ct) {
            f32x4 acc = {0.f, 0.f, 0.f, 0.f};
            const int q = ct * 16 + lr;
            #pragma unroll
            for (int s = 0; s < 4; ++s) {
                short8 bf = *(const short8*)(smem + QH_OFF + SWZQ(q, q * 256 + s * 64 + lg * 16));
                acc = mfma16(a[s], bf, acc);
            }
            sim[ct] = acc;
        }
        const float scale = 0.08838834764831845f;  // 1/sqrt(128)
        #pragma unroll
        for (int ct = 0; ct < 4; ++ct) {
            const int q = ct * 16 + lr;
            #pragma unroll
            for (int r = 0; r < 4; ++r)
                sim[ct][r] = (q < nq) ? sim[ct][r] * scale : -3.0e38f;
        }
        float mx[4], sm[4];
        #pragma unroll
        for (int r = 0; r < 4; ++r)
            mx[r] = fmaxf(fmaxf(sim[0][r], sim[1][r]), fmaxf(sim[2][r], sim[3][r]));
        #pragma unroll
        for (int off = 1; off <= 8; off <<= 1)
            #pragma unroll
            for (int r = 0; r < 4; ++r)
                mx[r] = fmaxf(mx[r], __shfl_xor(mx[r], off));
        #pragma unroll
        for (int ct = 0; ct < 4; ++ct)
            #pragma unroll
            for (int r = 0; r < 4; ++r)
                sim[ct][r] = __expf(sim[ct][r] - mx[r]);
        #pragma unroll
        for (int r = 0; r < 4; ++r)
            sm[r] = (sim[0][r] + sim[1][r]) + (sim[2][r] + sim[3][r]);
        #pragma unroll
        for (int off = 1; off <= 8; off <<= 1)
            #pragma unroll
            for (int r = 0; r < 4; ++r)
                sm[r] += __shfl_xor(sm[r], off);
        // att -> X (qsum partials consumed in P2; barrier above separates)
        const int cbase = w * 16 + lg * 4;
        #pragma unroll
        for (int ct = 0; ct < 4; ++ct)
            #pragma unroll
            for (int r = 0; r < 4; ++r) {
                int c = cbase + r, q = ct * 16 + lr;
                *(unsigned short*)(smem + X_OFF + SWZ8(c, c * 128 + q * 2)) =
                    f2bf(sim[ct][r] * (1.0f / sm[r]));
            }
    }
    __syncthreads();

    // ---------------- P4: weighted_q = att @ q_h ----------------
    f32x4 wqa[8];
    {
        short8 pa[2];
        const int arow = w * 16 + lr;
        #pragma unroll
        for (int s = 0; s < 2; ++s)
            pa[s] = *(const short8*)(smem + X_OFF + SWZ8(arow, arow * 128 + s * 64 + lg * 16));
        #pragma unroll
        for (int ct = 0; ct < 8; ++ct) {
            f32x4 acc = {0.f, 0.f, 0.f, 0.f};
            const int d = ct * 16 + lr;
            const int dlx = (d << 1) ^ (lg << 5);
            #pragma unroll
            for (int s = 0; s < 2; ++s) {
                const int qbase = (s << 5) + (lg << 3);
                short8 bf;
                #pragma unroll
                for (int j = 0; j < 8; ++j) {
                    // SWZQ(q, q*256 + d*2), q = qbase+j; (q&7)=j, ((q>>3)&3)=lg
                    int off = QH_OFF + ((qbase + j) << 8) + (dlx ^ (j << 4));
                    bf[j] = *(const short*)(smem + off);
                }
                acc = mfma16(pa[s], bf, acc);
            }
            wqa[ct] = acc;
        }
    }
    __syncthreads();   // all q_h/att reads done -> wq overwrites QH
    {
        const int cbase = w * 16 + lg * 4;
        #pragma unroll
        for (int ct = 0; ct < 8; ++ct)
            #pragma unroll
            for (int r = 0; r < 4; ++r) {
                int c = cbase + r, d = ct * 16 + lr;
                *(unsigned short*)(smem + QH_OFF + SWZQ(c, c * 256 + d * 2)) =
                    f2bf(wqa[ct][r]);
            }
    }
    __syncthreads();

    // ---------------- P5: column-split GEMM + tanh + W_o -------------------
    {
        f32x4 acc[4][2];
        #pragma unroll
        for (int rt = 0; rt < 4; ++rt) {
            acc[rt][0] = (f32x4){0.f, 0.f, 0.f, 0.f};
            acc[rt][1] = (f32x4){0.f, 0.f, 0.f, 0.f};
        }
        const int n0 = w * 32 + lr, n1 = n0 + 16;
        const int klane = lg * 8;
        short8 qsf[4];
        #pragma unroll
        for (int sk = 0; sk < 4; ++sk)
            qsf[sk] = *(const short8*)(qsum_ws + (b << 7) + sk * 32 + klane);
        const float bh0 = b_h[n0], bh1 = b_h[n1];
        const float wo0 = W_o[n0], wo1 = W_o[n1];

        for (int sk = 0; sk < 4; ++sk) {
            short8 B0[5], B1[5];
            #pragma unroll
            for (int p = 0; p < 5; ++p) {
                B0[p] = *(const short8*)(whT + n0 * 640 + p * 128 + sk * 32 + klane);
                B1[p] = *(const short8*)(whT + n1 * 640 + p * 128 + sk * 32 + klane);
            }
            #pragma unroll
            for (int rt = 0; rt < 4; ++rt) {
                const int row = rt * 16 + lr;
                short8 chf = *(const short8*)(smem + CH_OFF + SWZ8(row, row * 256 + sk * 64 + lg * 16));
                short8 wqf = *(const short8*)(smem + QH_OFF + SWZQ(row, row * 256 + sk * 64 + lg * 16));
                short8 prf, adf;
                #pragma unroll
                for (int e = 0; e < 8; ++e) {
                    float cv = bf2f((unsigned short)chf[e]);
                    float wv = bf2f((unsigned short)wqf[e]);
                    prf[e] = (short)f2bf(cv * wv);
                    adf[e] = (short)f2bf(fabsf(cv - wv));
                }
                acc[rt][0] = mfma16(qsf[sk], B0[0], acc[rt][0]);
                acc[rt][1] = mfma16(qsf[sk], B1[0], acc[rt][1]);
                acc[rt][0] = mfma16(chf,     B0[1], acc[rt][0]);
                acc[rt][1] = mfma16(chf,     B1[1], acc[rt][1]);
                acc[rt][0] = mfma16(wqf,     B0[2], acc[rt][0]);
                acc[rt][1] = mfma16(wqf,     B1[2], acc[rt][1]);
                acc[rt][0] = mfma16(prf,     B0[3], acc[rt][0]);
                acc[rt][1] = mfma16(prf,     B1[3], acc[rt][1]);
                acc[rt][0] = mfma16(adf,     B0[4], acc[rt][0]);
                acc[rt][1] = mfma16(adf,     B1[4], acc[rt][1]);
            }
        }

        #pragma unroll
        for (int rt = 0; rt < 4; ++rt)
            #pragma unroll
            for (int r = 0; r < 4; ++r) {
                float x0 = acc[rt][0][r] + bh0;
                float x1 = acc[rt][1][r] + bh1;
                float t0 = 1.0f - 2.0f / (__expf(2.0f * x0) + 1.0f);  // tanh
                float t1 = 1.0f - 2.0f / (__expf(2.0f * x1) + 1.0f);
                float po = t0 * wo0 + t1 * wo1;
                #pragma unroll
                for (int off = 1; off <= 8; off <<= 1)
                    po += __shfl_xor(po, off);
                if (lr == 0)
                    *(float*)(smem + X_OFF + (w * 64 + rt * 16 + lg * 4 + r) * 4) = po;
            }
    }
    __syncthreads();

    // ---------------- P6: combine wave partials ----------------
    if (tid < 64) {
        float o = b_o[0];
        #pragma unroll
        for (int w2 = 0; w2 < 4; ++w2)
            o += *(const float*)(smem + X_OFF + (w2 * 64 + tid) * 4);
        out[(b << 6) + tid] = o;
    }
}

extern "C" void kernel_launch(void* const* d_in, const int* in_sizes, int n_in,
                              void* d_out, int out_size, void* d_ws, size_t ws_size,
                              hipStream_t stream) {
    const int*   q_ids  = (const int*)d_in[0];
    const int*   c_ids  = (const int*)d_in[1];
    const int*   num_qs = (const int*)d_in[2];
    // d_in[3] num_cols: unused by the reference forward
    const float* embed  = (const float*)d_in[4];
    const float* W_h    = (const float*)d_in[5];
    const float* b_h    = (const float*)d_in[6];
    const float* W_o    = (const float*)d_in[7];
    const float* b_o    = (const float*)d_in[8];
    float*       out    = (float*)d_out;

    // ws: [0,160K) whT | [160K, 416K) qsum bf16 [1024][128] | [416K, +25.6M) ebf
    unsigned short* whT  = (unsigned short*)d_ws;
    unsigned short* qsum = (unsigned short*)((char*)d_ws + 163840);
    unsigned short* ebf  = (unsigned short*)((char*)d_ws + 425984);

    el_prep<<<320, 256, 0, stream>>>(W_h, whT);

    const bool bf16e = ws_size >= (size_t)(425984 + 100000 * 128 * 2);
    if (bf16e) {
        el_conv<<<6250, 256, 0, stream>>>(embed, ebf);
        el_main<true><<<1024, 256, 0, stream>>>(q_ids, c_ids, num_qs, embed, ebf,
                                                whT, qsum, b_h, W_o, b_o, out);
    } else {
        el_main<false><<<1024, 256, 0, stream>>>(q_ids, c_ids, num_qs, embed, ebf,
                                                 whT, qsum, b_h, W_o, b_o, out);
    }
}